// Round 2
// 2880.324 us; speedup vs baseline: 1.0111x; 1.0111x over previous
//
#include <hip/hip_runtime.h>

// Round 12: diagonal pipelining (R11 structure) + PROVEN 4-lane rec_body
// (R9/R10 math, verbatim) fused at uniform BLOCK=448.
//  - R11's 2-lane rec was mathematically wrong (pair butterfly summed
//    partials of DIFFERENT gates). Reverted to the 4-lane scheme.
//  - Per diagonal d: ONE fused gemm launch (xg for layer l, chunk d-l) +
//    ONE fused rec launch (block group g = layer g, chunk d-g).
//  - rec blocks: 7 waves, 72 VGPR, 1KB LDS -> 4 blocks/CU (one per layer)
//    co-resident; l1-l3 rec work hides under l0's per-step stalls.
//  - wave_act: waves containing no active lane skip the step body (but
//    still hit the barrier), so l1-l3 surplus waves burn no issue.
//  TC=64 so all per-layer chunk buffers are concurrently live (~84 MB ws).

#define BATCH 256
#define TFULL 1024
#define TC    64
#define NCHUNK (TFULL / TC)   // 16
#define NDIAG  (NCHUNK + 3)   // 19

__device__ __forceinline__ float fast_rcp(float x) {
    return __builtin_amdgcn_rcpf(x);
}

__device__ __forceinline__ float tanh_fast(float x) {
    float e = __expf(-2.0f * fabsf(x));
    float r = fast_rcp(1.0f + e);
    return copysignf(fmaf(2.0f, r, -1.0f), x);
}

// LDS-only barrier: does NOT drain vmcnt (global loads/stores stay in
// flight). Safe: the rec loop's barrier only orders the LDS h handoff.
__device__ __forceinline__ void lds_barrier() {
    asm volatile("s_waitcnt lgkmcnt(0)\n\ts_barrier" ::: "memory");
}

template<int CTRL>
__device__ __forceinline__ float dpp_add(float v) {
    int t = __builtin_amdgcn_update_dpp(0, __float_as_int(v), CTRL, 0xF, 0xF, true);
    return v + __int_as_float(t);
}
template<int CTRL>
__device__ __forceinline__ float dpp_mov(float v) {
    int t = __builtin_amdgcn_update_dpp(0, __float_as_int(v), CTRL, 0xF, 0xF, true);
    return __int_as_float(t);
}

// ---------------- Phase A: fused xg = x @ Wx + bias ----------------
template<int K, int N>
__device__ __forceinline__ void gemm_body(
    const float* __restrict__ x, int batchStride,
    const float* __restrict__ Wx,    // [K, N]
    const float* __restrict__ bias,  // [N]
    float* __restrict__ out,         // [B*TC, N]
    int lid, float* __restrict__ smem)
{
    constexpr int K4   = (K + 3) / 4;
    constexpr int SLAB = 64 * 4 + 4;
    constexpr int GX   = (N + 63) / 64;

    float* s_A = smem;               // K4 * SLAB
    float* s_B = smem + K4 * SLAB;   // K4*4 * 64

    const int n0   = (lid % GX) * 64;
    const int row0 = (lid / GX) * 64;
    const int tid  = threadIdx.x;
    const int tx   = tid & 15;
    const int ty   = tid >> 4;

    if constexpr ((K % 4) == 0) {
        for (int i = tid; i < 64 * (K / 4); i += 256) {
            const int row = i / (K / 4);
            const int k4  = i % (K / 4);
            const int gr  = row0 + row;
            const int b   = gr >> 6;       // TC = 64
            const int t   = gr & 63;
            float4 v = *(const float4*)(x + (size_t)b * batchStride + t * K + k4 * 4);
            *(float4*)(s_A + k4 * SLAB + row * 4) = v;
        }
    } else {
        for (int i = tid; i < 64 * K; i += 256) {
            const int row = i / K;
            const int k   = i % K;
            const int gr  = row0 + row;
            const int b   = gr >> 6;
            const int t   = gr & 63;
            s_A[(k >> 2) * SLAB + row * 4 + (k & 3)] =
                x[(size_t)b * batchStride + t * K + k];
        }
        constexpr int PAD = K4 * 4 - K;
        for (int i = tid; i < 64 * PAD; i += 256) {
            const int row = i / PAD;
            const int kk  = K + i % PAD;
            s_A[(kk >> 2) * SLAB + row * 4 + (kk & 3)] = 0.0f;
        }
    }

    for (int i = tid; i < K4 * 4 * 16; i += 256) {
        const int k  = i >> 4;
        const int c4 = i & 15;
        float4 v = {0.0f, 0.0f, 0.0f, 0.0f};
        if (k < K && n0 + c4 * 4 < N)
            v = *(const float4*)(Wx + (size_t)k * N + n0 + c4 * 4);
        *(float4*)(s_B + k * 64 + c4 * 4) = v;
    }
    __syncthreads();

    float acc[4][4];
#pragma unroll
    for (int r = 0; r < 4; ++r)
#pragma unroll
        for (int c = 0; c < 4; ++c) acc[r][c] = 0.0f;

    for (int k4 = 0; k4 < K4; ++k4) {
        float4 bv[4];
#pragma unroll
        for (int j = 0; j < 4; ++j)
            bv[j] = *(const float4*)(s_B + (k4 * 4 + j) * 64 + tx * 4);
#pragma unroll
        for (int r = 0; r < 4; ++r) {
            float4 av = *(const float4*)(s_A + k4 * SLAB + (ty + 16 * r) * 4);
#pragma unroll
            for (int c = 0; c < 4; ++c) {
                acc[r][c] = fmaf(av.x, ((const float*)&bv[0])[c], acc[r][c]);
                acc[r][c] = fmaf(av.y, ((const float*)&bv[1])[c], acc[r][c]);
                acc[r][c] = fmaf(av.z, ((const float*)&bv[2])[c], acc[r][c]);
                acc[r][c] = fmaf(av.w, ((const float*)&bv[3])[c], acc[r][c]);
            }
        }
    }

    if (n0 + tx * 4 < N) {
        float4 bb = *(const float4*)(bias + n0 + tx * 4);
#pragma unroll
        for (int r = 0; r < 4; ++r) {
            float4 o;
            o.x = acc[r][0] + bb.x;
            o.y = acc[r][1] + bb.y;
            o.z = acc[r][2] + bb.z;
            o.w = acc[r][3] + bb.w;
            *(float4*)(out + (size_t)(row0 + ty + 16 * r) * N + n0 + tx * 4) = o;
        }
    }
}

struct GemmArgs {
    const float *x0, *x1, *x2, *x3;
    float *o0, *o1, *o2, *o3;
    const float *Wx0, *bi0, *Wx1, *bi1, *Wx2, *bi2, *Wx3, *bi3;
    int off1, off2, off3;
};

// max smem: K=100 -> K4=25 -> 25*(260+256) = 12900 floats (51.6 KB)
__global__ __launch_bounds__(256, 2)
void xg_all(GemmArgs a)
{
    __shared__ __align__(16) float smem[12900];
    const int bid = blockIdx.x;
    if (bid < a.off1)
        gemm_body<64, 400>(a.x0, TFULL * 64, a.Wx0, a.bi0, a.o0, bid, smem);
    else if (bid < a.off2)
        gemm_body<100, 320>(a.x1, TC * 100, a.Wx1, a.bi1, a.o1, bid - a.off1, smem);
    else if (bid < a.off3)
        gemm_body<80, 200>(a.x2, TC * 80, a.Wx2, a.bi2, a.o2, bid - a.off2, smem);
    else
        gemm_body<50, 120>(a.x3, TC * 50, a.Wx3, a.bi3, a.o3, bid - a.off3, smem);
}

// ---------------- Phase B: recurrence body (PROVEN 4-lane scheme) ----------
// 4 lanes per unit (quad-aligned). S: per-lane k-slice (mult of 4, 4*S >= U).
// Identical math to the R9/R10 passing kernel; only changes: LDS via pointer
// with HS=4*S stride, uniform BLOCK, wave-uniform skip for inactive waves.
template<int U, int S, int BLOCK, bool LAST>
__device__ __forceinline__ void rec4_body(
    float* __restrict__ s_h,        // [2][4*S] in LDS (pointer, stride HS)
    const float* __restrict__ xg,   // [B, TC, G]
    const float* __restrict__ Wh,   // [U, G]
    float* __restrict__ xout,       // [B, TC, U] (unless LAST)
    float* __restrict__ c_state,    // [B*U]
    float* __restrict__ h_state,    // [B*U]
    int first, int b,
    const float* __restrict__ Wout, // [U] (LAST)
    const float* __restrict__ bout, // [1] (LAST)
    float* __restrict__ dout)       // [B] (LAST)
{
    constexpr int G  = 4 * U;
    constexpr int HS = 4 * S;

    const int tid = threadIdx.x;
    const int u   = tid >> 2;
    const int s   = tid & 3;
    const bool act_th = (u < U);
    const int uu  = act_th ? u : 0;
    // wave-uniform: does this wave contain any active lane?
    const bool wave_act = ((tid & ~63) < 4 * U);

    float w4[4][S];
#pragma unroll
    for (int g = 0; g < 4; ++g)
#pragma unroll
        for (int kk = 0; kk < S; ++kk) {
            const int k = s * S + kk;
            w4[g][kk] = (act_th && k < U) ? Wh[(size_t)k * G + g * U + uu] : 0.0f;
        }

    for (int i = tid; i < 2 * HS; i += BLOCK) s_h[i] = 0.0f;
    __syncthreads();
    if (tid < U) s_h[tid] = first ? 0.0f : h_state[b * U + tid];
    float c = first ? 0.0f : c_state[b * U + uu];
    __syncthreads();

    const float* xgp = xg + (size_t)b * TC * G + (s * U + uu);
    float xg0 = xgp[0];
    float xg1 = xgp[G];

    int cur = 0;
    float h = 0.0f, hprev = 0.0f;
    const bool is_t = (s == 2);

    for (int t = 0; t < TC; ++t, cur ^= 1) {
        if (wave_act) {
            // (1) t+2 prefetch: waited at USE two steps from now
            const int tp = (t + 2 < TC) ? (t + 2) : (TC - 1);
            const float xg2 = xgp[(size_t)tp * G];

            // (2) deferred global store of last step's h (never waited at barrier)
            if (!LAST) {
                if (act_th && s == 0 && t > 0)
                    xout[((size_t)b * TC + (t - 1)) * U + u] = hprev;
            }

            // (3) partial dots over this lane's k-slice, all 4 gates
            float a0 = 0.0f, a1 = 0.0f, a2 = 0.0f, a3 = 0.0f;
            const float* hs = s_h + cur * HS + s * S;
#pragma unroll
            for (int kk = 0; kk < S; kk += 4) {
                float4 v = *(const float4*)(hs + kk);
                a0 = fmaf(v.x, w4[0][kk + 0], a0);
                a0 = fmaf(v.y, w4[0][kk + 1], a0);
                a0 = fmaf(v.z, w4[0][kk + 2], a0);
                a0 = fmaf(v.w, w4[0][kk + 3], a0);
                a1 = fmaf(v.x, w4[1][kk + 0], a1);
                a1 = fmaf(v.y, w4[1][kk + 1], a1);
                a1 = fmaf(v.z, w4[1][kk + 2], a1);
                a1 = fmaf(v.w, w4[1][kk + 3], a1);
                a2 = fmaf(v.x, w4[2][kk + 0], a2);
                a2 = fmaf(v.y, w4[2][kk + 1], a2);
                a2 = fmaf(v.z, w4[2][kk + 2], a2);
                a2 = fmaf(v.w, w4[2][kk + 3], a2);
                a3 = fmaf(v.x, w4[3][kk + 0], a3);
                a3 = fmaf(v.y, w4[3][kk + 1], a3);
                a3 = fmaf(v.z, w4[3][kk + 2], a3);
                a3 = fmaf(v.w, w4[3][kk + 3], a3);
            }

            // (4) quad butterfly
            a0 = dpp_add<0xB1>(a0); a0 = dpp_add<0x4E>(a0);
            a1 = dpp_add<0xB1>(a1); a1 = dpp_add<0x4E>(a1);
            a2 = dpp_add<0xB1>(a2); a2 = dpp_add<0x4E>(a2);
            a3 = dpp_add<0xB1>(a3); a3 = dpp_add<0x4E>(a3);

            // (5) lane s finalizes gate s (distributed activation)
            const float asum = (s == 0) ? a0 : (s == 1) ? a1 : (s == 2) ? a2 : a3;
            const float gs = asum + xg0;
            const float y  = is_t ? (-2.0f * fabsf(gs)) : (-gs);
            const float r  = fast_rcp(1.0f + __expf(y));
            const float v  = is_t ? copysignf(fmaf(2.0f, r, -1.0f), gs) : r;

            // (6) gather quad activations, update c/h (replicated)
            const float fi = dpp_mov<0x00>(v);
            const float ff = dpp_mov<0x55>(v);
            const float tc = dpp_mov<0xAA>(v);
            const float fo = dpp_mov<0xFF>(v);
            c = fmaf(ff, c, fi * tc);
            h = fo * tanh_fast(c);

            const int nxt = cur ^ 1;
            if (act_th && s == 0) s_h[nxt * HS + u] = h;
            hprev = h;
            xg0 = xg1; xg1 = xg2;
        }
        lds_barrier();   // LDS-only: global ops stay in flight
    }

    if (!LAST) {
        if (act_th && s == 0)
            xout[((size_t)b * TC + (TC - 1)) * U + u] = hprev;
    }
    if (act_th && s == 0) {
        c_state[b * U + u] = c;
        h_state[b * U + u] = h;
    }
    if (LAST && tid == 0) {
        float acc = bout[0];
#pragma unroll
        for (int k = 0; k < U; ++k) acc = fmaf(s_h[cur * HS + k], Wout[k], acc);
        dout[b] = acc;
    }
}

struct RecArgs {
    const float *xg0, *xg1, *xg2, *xg3;
    const float *Wh0, *Wh1, *Wh2, *Wh3;
    float *xc0, *xc1, *xc2;
    float *c0, *h0, *c1, *h1, *c2, *h2, *c3, *h3;
    const float *Wout, *bout;
    float *dout;
    int d;
};

// Block group g (bid>>8) = layer g, batch b = bid&255, chunk j = d - g.
// 7-wave blocks, 72 VGPR, 1KB LDS -> 4 blocks (one per layer) co-resident
// per CU (28 waves); l1-l3 rec work hides under l0's per-step stalls.
__global__ __attribute__((amdgpu_flat_work_group_size(448, 448),
                          amdgpu_waves_per_eu(4, 8)))
void rec_all(RecArgs a)
{
    __shared__ __align__(16) float s_h[2 * 112];   // max branch: U=100, S=28
    const int grp = blockIdx.x >> 8;
    const int b   = blockIdx.x & 255;
    const int j   = a.d - grp;
    if (j < 0 || j >= NCHUNK) return;
    const int first = (j == 0) ? 1 : 0;
    switch (grp) {
    case 0: rec4_body<100, 28, 448, false>(s_h, a.xg0, a.Wh0, a.xc0, a.c0, a.h0,
                                           first, b, nullptr, nullptr, nullptr); break;
    case 1: rec4_body< 80, 20, 448, false>(s_h, a.xg1, a.Wh1, a.xc1, a.c1, a.h1,
                                           first, b, nullptr, nullptr, nullptr); break;
    case 2: rec4_body< 50, 16, 448, false>(s_h, a.xg2, a.Wh2, a.xc2, a.c2, a.h2,
                                           first, b, nullptr, nullptr, nullptr); break;
    default: rec4_body< 30,  8, 448, true >(s_h, a.xg3, a.Wh3, nullptr, a.c3, a.h3,
                                           first, b, a.Wout, a.bout, a.dout); break;
    }
}

extern "C" void kernel_launch(void* const* d_in, const int* in_sizes, int n_in,
                              void* d_out, int out_size, void* d_ws, size_t ws_size,
                              hipStream_t stream)
{
    const float* seq  = (const float*)d_in[0];
    const float* Wx0  = (const float*)d_in[1];
    const float* Wh0  = (const float*)d_in[2];
    const float* b0   = (const float*)d_in[3];
    const float* Wx1  = (const float*)d_in[4];
    const float* Wh1  = (const float*)d_in[5];
    const float* b1   = (const float*)d_in[6];
    const float* Wx2  = (const float*)d_in[7];
    const float* Wh2  = (const float*)d_in[8];
    const float* b2   = (const float*)d_in[9];
    const float* Wx3  = (const float*)d_in[10];
    const float* Wh3  = (const float*)d_in[11];
    const float* b3   = (const float*)d_in[12];
    const float* Wout = (const float*)d_in[13];
    const float* bout = (const float*)d_in[14];
    float* out = (float*)d_out;

    // workspace: all per-layer chunk buffers concurrently live (~84 MB)
    float* ws  = (float*)d_ws;
    float* XG0 = ws;
    float* XG1 = XG0 + (size_t)BATCH * TC * 400;
    float* XG2 = XG1 + (size_t)BATCH * TC * 320;
    float* XG3 = XG2 + (size_t)BATCH * TC * 200;
    float* XC0 = XG3 + (size_t)BATCH * TC * 120;
    float* XC1 = XC0 + (size_t)BATCH * TC * 100;
    float* XC2 = XC1 + (size_t)BATCH * TC * 80;
    float* st  = XC2 + (size_t)BATCH * TC * 50;
    float* sc0 = st + 0 * 32768; float* sh0 = st + 1 * 32768;
    float* sc1 = st + 2 * 32768; float* sh1 = st + 3 * 32768;
    float* sc2 = st + 4 * 32768; float* sh2 = st + 5 * 32768;
    float* sc3 = st + 6 * 32768; float* sh3 = st + 7 * 32768;

    // gemm block counts per layer: GX * (B*TC/64) = GX * 256
    const int NB0 = 7 * 256, NB1 = 5 * 256, NB2 = 4 * 256, NB3 = 2 * 256;

    for (int d = 0; d < NDIAG; ++d) {
        GemmArgs ga;
        ga.x0 = nullptr; ga.x1 = nullptr; ga.x2 = nullptr; ga.x3 = nullptr;
        ga.o0 = XG0; ga.o1 = XG1; ga.o2 = XG2; ga.o3 = XG3;
        ga.Wx0 = Wx0; ga.bi0 = b0; ga.Wx1 = Wx1; ga.bi1 = b1;
        ga.Wx2 = Wx2; ga.bi2 = b2; ga.Wx3 = Wx3; ga.bi3 = b3;
        int nb = 0;
        if (d < NCHUNK)                { ga.x0 = seq + (size_t)d * TC * 64; nb += NB0; }
        ga.off1 = nb;
        if (d >= 1 && d - 1 < NCHUNK)  { ga.x1 = XC0; nb += NB1; }
        ga.off2 = nb;
        if (d >= 2 && d - 2 < NCHUNK)  { ga.x2 = XC1; nb += NB2; }
        ga.off3 = nb;
        if (d >= 3 && d - 3 < NCHUNK)  { ga.x3 = XC2; nb += NB3; }

        xg_all<<<dim3(nb), dim3(256), 0, stream>>>(ga);

        RecArgs ra;
        ra.xg0 = XG0; ra.xg1 = XG1; ra.xg2 = XG2; ra.xg3 = XG3;
        ra.Wh0 = Wh0; ra.Wh1 = Wh1; ra.Wh2 = Wh2; ra.Wh3 = Wh3;
        ra.xc0 = XC0; ra.xc1 = XC1; ra.xc2 = XC2;
        ra.c0 = sc0; ra.h0 = sh0; ra.c1 = sc1; ra.h1 = sh1;
        ra.c2 = sc2; ra.h2 = sh2; ra.c3 = sc3; ra.h3 = sh3;
        ra.Wout = Wout; ra.bout = bout; ra.dout = out;
        ra.d = d;

        rec_all<<<dim3(4 * 256), dim3(448), 0, stream>>>(ra);
    }
}